// Round 1
// baseline (284.668 us; speedup 1.0000x reference)
//
#include <hip/hip_runtime.h>
#include <hip/hip_bf16.h>

#define B_TOTAL 2048
#define H 128
#define NL 64
#define NPAIRS 512
#define K1_BLOCKS 1024
#define BPB 2            // batches per block: K1_BLOCKS * BPB == B_TOTAL
#define K1_THREADS 256

// ---------------------------------------------------------------------------
// Kernel 0: build CSR of pairs grouped by first index i (values < 64).
// ws layout: int offs[65]; int cols[512]
// ---------------------------------------------------------------------------
__global__ void build_csr_kernel(const int* __restrict__ pairs,
                                 int* __restrict__ ws_offs,
                                 int* __restrict__ ws_cols) {
    __shared__ int cnt[NL];
    __shared__ int offs_s[NL + 1];
    __shared__ int cur[NL];
    const int tid = threadIdx.x;

    if (tid < NL) cnt[tid] = 0;
    __syncthreads();

    for (int e = tid; e < NPAIRS; e += blockDim.x) {
        int i = pairs[2 * e] & (NL - 1);   // defensive mask, values are < 64
        atomicAdd(&cnt[i], 1);
    }
    __syncthreads();

    if (tid == 0) {
        int run = 0;
        for (int r = 0; r < NL; ++r) { offs_s[r] = run; run += cnt[r]; }
        offs_s[NL] = run;
    }
    __syncthreads();

    if (tid < NL) cur[tid] = offs_s[tid];
    __syncthreads();

    for (int e = tid; e < NPAIRS; e += blockDim.x) {
        int i = pairs[2 * e] & (NL - 1);
        int j = pairs[2 * e + 1] & (NL - 1);
        int pos = atomicAdd(&cur[i], 1);
        ws_cols[pos] = j;
    }
    if (tid < NL + 1) ws_offs[tid] = offs_s[tid];
}

// ---------------------------------------------------------------------------
// Kernel 1: per block, for BPB batches:
//   stage A = P[b, 0:64, :] (contiguous 32KB) into LDS,
//   form Y[i,:] = sum_{e: i_e = i} A[j_e,:]   (two 32-row halves),
//   accumulate per-thread 8x8 tile of T += A^T Y  (rank-64 update),
// epilogue: dot per-thread tile with D tile, block-reduce, one atomicAdd.
// ---------------------------------------------------------------------------
__global__ __launch_bounds__(K1_THREADS, 3)
void edge_loss_kernel(const float* __restrict__ P,
                      const float* __restrict__ D,
                      const int* __restrict__ ws_offs,
                      const int* __restrict__ ws_cols,
                      float* __restrict__ out) {
    __shared__ float As[NL][H];          // 32 KB
    __shared__ float Yh[NL / 2][H];      // 16 KB (one 32-row half at a time)
    __shared__ int   offs[NL + 1];
    __shared__ int   cols[NPAIRS];
    __shared__ float wsum[K1_THREADS / 64];

    const int tid = threadIdx.x;

    // copy CSR to LDS (visible after first __syncthreads below)
    if (tid < NL + 1) offs[tid] = ws_offs[tid];
    for (int s = tid; s < NPAIRS; s += K1_THREADS) cols[s] = ws_cols[s];

    const int tp = tid >> 4;          // 0..15
    const int tq = tid & 15;          // 0..15
    const int p0 = tp * 8;
    const int q0 = tq * 8;

    float acc[8][8];
#pragma unroll
    for (int u = 0; u < 8; ++u)
#pragma unroll
        for (int v = 0; v < 8; ++v) acc[u][v] = 0.f;

    const int q     = tid & (H - 1);  // 0..127 (for Y formation)
    const int rbase = tid >> 7;       // 0 or 1

    for (int bb = 0; bb < BPB; ++bb) {
        const int b = blockIdx.x * BPB + bb;
        // A = P[b, 0:64, :] is the first 64*128 floats of P[b] -> contiguous 32KB
        const float4* src = reinterpret_cast<const float4*>(P + (size_t)b * H * H);
        float4* dstA = reinterpret_cast<float4*>(&As[0][0]);
#pragma unroll
        for (int k = 0; k < (NL * H / 4) / K1_THREADS; ++k) {   // 8 iters
            dstA[tid + k * K1_THREADS] = src[tid + k * K1_THREADS];
        }
        __syncthreads();

        for (int hf = 0; hf < 2; ++hf) {
            // ---- form Y rows [hf*32, hf*32+32) ----
            for (int pass = 0; pass < 16; ++pass) {
                const int r_local = pass * 2 + rbase;
                const int r = hf * 32 + r_local;
                const int s0 = offs[r], s1 = offs[r + 1];
                float y = 0.f;
                for (int s = s0; s < s1; ++s) y += As[cols[s]][q];
                Yh[r_local][q] = y;
            }
            __syncthreads();

            // ---- T += A[hf-half]^T * Yh : 32 rank-1 updates ----
#pragma unroll 4
            for (int il = 0; il < 32; ++il) {
                const int i = hf * 32 + il;
                float4 a0 = *reinterpret_cast<const float4*>(&As[i][p0]);
                float4 a1 = *reinterpret_cast<const float4*>(&As[i][p0 + 4]);
                float4 y0 = *reinterpret_cast<const float4*>(&Yh[il][q0]);
                float4 y1 = *reinterpret_cast<const float4*>(&Yh[il][q0 + 4]);
                float av[8] = {a0.x, a0.y, a0.z, a0.w, a1.x, a1.y, a1.z, a1.w};
                float yv[8] = {y0.x, y0.y, y0.z, y0.w, y1.x, y1.y, y1.z, y1.w};
#pragma unroll
                for (int u = 0; u < 8; ++u)
#pragma unroll
                    for (int v = 0; v < 8; ++v)
                        acc[u][v] = fmaf(av[u], yv[v], acc[u][v]);
            }
            __syncthreads();   // Yh (and, on hf==1, As) about to be overwritten
        }
    }

    // ---- epilogue: dot with D tile, reduce, atomic add ----
    float s = 0.f;
#pragma unroll
    for (int u = 0; u < 8; ++u) {
        float4 d0 = *reinterpret_cast<const float4*>(&D[(size_t)(p0 + u) * H + q0]);
        float4 d1 = *reinterpret_cast<const float4*>(&D[(size_t)(p0 + u) * H + q0 + 4]);
        float dv[8] = {d0.x, d0.y, d0.z, d0.w, d1.x, d1.y, d1.z, d1.w};
#pragma unroll
        for (int v = 0; v < 8; ++v) s = fmaf(acc[u][v], dv[v], s);
    }
#pragma unroll
    for (int off = 32; off > 0; off >>= 1) s += __shfl_down(s, off, 64);

    const int wid = tid >> 6, lane = tid & 63;
    if (lane == 0) wsum[wid] = s;
    __syncthreads();
    if (tid == 0) {
        float t = 0.f;
#pragma unroll
        for (int w = 0; w < K1_THREADS / 64; ++w) t += wsum[w];
        atomicAdd(out, t * (1.0f / ((float)B_TOTAL * (float)NPAIRS)));
    }
}

extern "C" void kernel_launch(void* const* d_in, const int* in_sizes, int n_in,
                              void* d_out, int out_size, void* d_ws, size_t ws_size,
                              hipStream_t stream) {
    const float* P     = (const float*)d_in[0];
    const float* D     = (const float*)d_in[1];
    const int*   pairs = (const int*)d_in[2];
    // d_in[3] = num_logical (scalar, == 64) -- hardcoded as NL
    float* out = (float*)d_out;

    int* ws_offs = (int*)d_ws;
    int* ws_cols = ws_offs + (NL + 1);

    hipMemsetAsync(d_out, 0, sizeof(float), stream);
    build_csr_kernel<<<1, 256, 0, stream>>>(pairs, ws_offs, ws_cols);
    edge_loss_kernel<<<K1_BLOCKS, K1_THREADS, 0, stream>>>(P, D, ws_offs, ws_cols, out);
}

// Round 2
// 197.327 us; speedup vs baseline: 1.4426x; 1.4426x over previous
//
#include <hip/hip_runtime.h>
#include <hip/hip_bf16.h>

#define B_TOTAL 2048
#define H 128
#define NL 64
#define NPAIRS 512
#define BPB 2
#define K1_BLOCKS (B_TOTAL / BPB)
#define AT_STRIDE 72   // bf16 elems; 144B row stride, 16B-aligned, breaks pow2 banks
#define S_STRIDE 72

typedef __attribute__((ext_vector_type(8))) short bf16x8;  // 8 bf16 = 4 VGPR (MFMA A/B frag)
typedef __attribute__((ext_vector_type(4))) float f32x4;   // MFMA C/D frag

static __device__ __forceinline__ ushort f2bf(float f) {
    // round-to-nearest-even fp32 -> bf16 (inputs finite, no NaN handling needed)
    uint u = __float_as_uint(f);
    u += 0x7fffu + ((u >> 16) & 1u);
    return (ushort)(u >> 16);
}

// ---------------------------------------------------------------------------
// Kernel 0: build dense bf16 count matrix S[64][72-padded]:
//   S[i][j] = number of edges e with (i_e, j_e) == (i, j).
// Pairs arrive as int32 (harness converts int64 -> int32): pairs[2e], pairs[2e+1].
// ---------------------------------------------------------------------------
__global__ void build_S_kernel(const int* __restrict__ pairs,
                               ushort* __restrict__ S_bf) {
    __shared__ int cnt[NL * NL];
    const int tid = threadIdx.x;
    for (int k = tid; k < NL * NL; k += 256) cnt[k] = 0;
    __syncthreads();
    for (int e = tid; e < NPAIRS; e += 256) {
        int i = pairs[2 * e] & (NL - 1);
        int j = pairs[2 * e + 1] & (NL - 1);
        atomicAdd(&cnt[i * NL + j], 1);
    }
    __syncthreads();
    for (int k = tid; k < NL * S_STRIDE; k += 256) {
        int r = k / S_STRIDE, c = k - r * S_STRIDE;
        float v = (c < NL) ? (float)cnt[r * NL + c] : 0.0f;
        S_bf[k] = f2bf(v);
    }
}

// ---------------------------------------------------------------------------
// Kernel 1: per block (BPB batches):
//  p1: stage A = P[b, :64, :] fp32 -> LDS (coalesced float4)
//  p2: transpose+convert -> ATb[q][i] bf16
//  p3: YT = AT * S^T via MFMA (wave-private q-rows, no barrier)
//  p4: G += AT * YT^T via MFMA, accumulated in registers across batches
//  epilogue: s = <D, G> partial per thread, block reduce, one atomicAdd
// ---------------------------------------------------------------------------
__global__ __launch_bounds__(256, 2)
void edge_loss_mfma(const float* __restrict__ P,
                    const float* __restrict__ D,
                    const ushort* __restrict__ S_ws,
                    float* __restrict__ out) {
    __shared__ float  As[NL][H];            // 32 KB fp32 staging of A (64x128)
    __shared__ ushort ATb[H][AT_STRIDE];    // 18 KB bf16 AT[q][i] = A[i][q]
    __shared__ ushort YTb[H][AT_STRIDE];    // 18 KB bf16 YT[q][i] = Y[i][q]
    __shared__ ushort Sb[NL][S_STRIDE];     //  9 KB bf16 S[i][j]
    __shared__ float  wsum[4];

    const int tid  = threadIdx.x;
    const int lane = tid & 63;
    const int w    = tid >> 6;              // wave 0..3; owns q-tiles {2w, 2w+1}
    const int l15  = lane & 15;
    const int lg   = lane >> 4;             // 0..3

    // stage S (constant across batches) into LDS
    {
        const uint* src = reinterpret_cast<const uint*>(S_ws);
        uint* dst = reinterpret_cast<uint*>(&Sb[0][0]);
        for (int k = tid; k < NL * S_STRIDE / 2; k += 256) dst[k] = src[k];
    }

    f32x4 acc[8][2];                        // G frags: [p-tile][local q-tile]
#pragma unroll
    for (int a = 0; a < 8; ++a) {
        acc[a][0] = (f32x4)0.0f;
        acc[a][1] = (f32x4)0.0f;
    }

    for (int bb = 0; bb < BPB; ++bb) {
        const int b = blockIdx.x * BPB + bb;

        // ---- p1: stage A (first 64 rows of P[b] are contiguous 32KB) ----
        {
            const float4* src = reinterpret_cast<const float4*>(P + (size_t)b * H * H);
            float4* dst = reinterpret_cast<float4*>(&As[0][0]);
#pragma unroll
            for (int k = 0; k < 8; ++k) dst[tid + k * 256] = src[tid + k * 256];
        }
        __syncthreads();

        // ---- p2: transpose+convert: ATb[q][i] = bf16(As[i][q]) ----
        {
            const int q  = tid >> 1;
            const int i0 = (tid & 1) * 32;
#pragma unroll
            for (int g = 0; g < 4; ++g) {
                const int ib = i0 + g * 8;
                uint4 v;
                v.x = (uint)f2bf(As[ib + 0][q]) | ((uint)f2bf(As[ib + 1][q]) << 16);
                v.y = (uint)f2bf(As[ib + 2][q]) | ((uint)f2bf(As[ib + 3][q]) << 16);
                v.z = (uint)f2bf(As[ib + 4][q]) | ((uint)f2bf(As[ib + 5][q]) << 16);
                v.w = (uint)f2bf(As[ib + 6][q]) | ((uint)f2bf(As[ib + 7][q]) << 16);
                *reinterpret_cast<uint4*>(&ATb[q][ib]) = v;
            }
        }
        __syncthreads();

        // ---- p3: YT = AT * S^T  (this wave's q-rows [32w, 32w+32) only) ----
        {
            f32x4 yt[2][4];
#pragma unroll
            for (int m = 0; m < 2; ++m)
#pragma unroll
                for (int nt = 0; nt < 4; ++nt) yt[m][nt] = (f32x4)0.0f;

#pragma unroll
            for (int ks = 0; ks < 2; ++ks) {
                const int kcol = ks * 32 + lg * 8;
                bf16x8 a0 = *reinterpret_cast<const bf16x8*>(&ATb[(2 * w + 0) * 16 + l15][kcol]);
                bf16x8 a1 = *reinterpret_cast<const bf16x8*>(&ATb[(2 * w + 1) * 16 + l15][kcol]);
#pragma unroll
                for (int nt = 0; nt < 4; ++nt) {
                    bf16x8 sf = *reinterpret_cast<const bf16x8*>(&Sb[nt * 16 + l15][kcol]);
                    yt[0][nt] = __builtin_amdgcn_mfma_f32_16x16x32_bf16(a0, sf, yt[0][nt], 0, 0, 0);
                    yt[1][nt] = __builtin_amdgcn_mfma_f32_16x16x32_bf16(a1, sf, yt[1][nt], 0, 0, 0);
                }
            }
            // write YT frags -> LDS (own rows; same-wave ordering via lgkmcnt)
#pragma unroll
            for (int m = 0; m < 2; ++m)
#pragma unroll
                for (int nt = 0; nt < 4; ++nt)
#pragma unroll
                    for (int r = 0; r < 4; ++r) {
                        const int qrow = (2 * w + m) * 16 + lg * 4 + r;
                        YTb[qrow][nt * 16 + l15] = f2bf(yt[m][nt][r]);
                    }
        }

        // ---- p4: G += AT * YT^T  (K = i = 64, two k-steps) ----
#pragma unroll
        for (int ks = 0; ks < 2; ++ks) {
            const int kcol = ks * 32 + lg * 8;
            bf16x8 b0 = *reinterpret_cast<const bf16x8*>(&YTb[(2 * w + 0) * 16 + l15][kcol]);
            bf16x8 b1 = *reinterpret_cast<const bf16x8*>(&YTb[(2 * w + 1) * 16 + l15][kcol]);
#pragma unroll
            for (int pt = 0; pt < 8; ++pt) {
                bf16x8 af = *reinterpret_cast<const bf16x8*>(&ATb[pt * 16 + l15][kcol]);
                acc[pt][0] = __builtin_amdgcn_mfma_f32_16x16x32_bf16(af, b0, acc[pt][0], 0, 0, 0);
                acc[pt][1] = __builtin_amdgcn_mfma_f32_16x16x32_bf16(af, b1, acc[pt][1], 0, 0, 0);
            }
        }
        __syncthreads();   // all waves done with ATb before next batch rewrites it
    }

    // ---- epilogue: <D, G> ----
    float s = 0.0f;
#pragma unroll
    for (int pt = 0; pt < 8; ++pt) {
#pragma unroll
        for (int nq = 0; nq < 2; ++nq) {
            const int col  = (2 * w + nq) * 16 + l15;
            const int row0 = pt * 16 + lg * 4;
#pragma unroll
            for (int r = 0; r < 4; ++r)
                s = fmaf(acc[pt][nq][r], D[(size_t)(row0 + r) * H + col], s);
        }
    }
#pragma unroll
    for (int off = 32; off > 0; off >>= 1) s += __shfl_down(s, off, 64);

    if (lane == 0) wsum[w] = s;
    __syncthreads();
    if (tid == 0) {
        float t = wsum[0] + wsum[1] + wsum[2] + wsum[3];
        atomicAdd(out, t * (1.0f / ((float)B_TOTAL * (float)NPAIRS)));
    }
}

extern "C" void kernel_launch(void* const* d_in, const int* in_sizes, int n_in,
                              void* d_out, int out_size, void* d_ws, size_t ws_size,
                              hipStream_t stream) {
    const float* P     = (const float*)d_in[0];
    const float* D     = (const float*)d_in[1];
    const int*   pairs = (const int*)d_in[2];
    float* out = (float*)d_out;

    ushort* S_bf = (ushort*)d_ws;   // 64*72*2 = 9216 bytes

    hipMemsetAsync(d_out, 0, sizeof(float), stream);
    build_S_kernel<<<1, 256, 0, stream>>>(pairs, S_bf);
    edge_loss_mfma<<<K1_BLOCKS, 256, 0, stream>>>(P, D, S_bf, out);
}

// Round 3
// 192.634 us; speedup vs baseline: 1.4778x; 1.0244x over previous
//
#include <hip/hip_runtime.h>
#include <hip/hip_bf16.h>

#define B_TOTAL 2048
#define H 128
#define NL 64
#define NPAIRS 512
#define BPB 2
#define NBLOCKS (B_TOTAL / BPB)

typedef __attribute__((ext_vector_type(8))) short bf16x8;  // MFMA A/B frag (8 bf16)
typedef __attribute__((ext_vector_type(4))) float f32x4;   // MFMA C/D frag

static __device__ __forceinline__ ushort f2bf(float f) {
    uint u = __float_as_uint(f);
    u += 0x7fffu + ((u >> 16) & 1u);   // RNE
    return (ushort)(u >> 16);
}
static __device__ __forceinline__ uint pk2bf(float x, float y) {
    return (uint)f2bf(x) | ((uint)f2bf(y) << 16);
}

// ---------------------------------------------------------------------------
// prep: block 0 builds S (edge-count matrix) as f32; blocks 1..64 convert
// D (symmetric 128x128 f32) to bf16 row-major.
// ws layout: float Sf[64*64] ; ushort Dbf[128*128]
// ---------------------------------------------------------------------------
__global__ void prep_kernel(const int* __restrict__ pairs,
                            const float* __restrict__ Dsrc,
                            float* __restrict__ Sf,
                            ushort* __restrict__ Dbf) {
    const int tid = threadIdx.x;
    if (blockIdx.x == 0) {
        __shared__ int cnt[NL * NL];
        for (int k = tid; k < NL * NL; k += 256) cnt[k] = 0;
        __syncthreads();
        for (int e = tid; e < NPAIRS; e += 256) {
            int i = pairs[2 * e] & (NL - 1);
            int j = pairs[2 * e + 1] & (NL - 1);
            atomicAdd(&cnt[i * NL + j], 1);
        }
        __syncthreads();
        for (int k = tid; k < NL * NL; k += 256) Sf[k] = (float)cnt[k];
    } else {
        int k = (blockIdx.x - 1) * 256 + tid;   // 64 blocks * 256 = 16384 = H*H
        Dbf[k] = f2bf(Dsrc[k]);
    }
}

// ---------------------------------------------------------------------------
// main: per batch b (2 per block):  U = A_b * D  (64x128x128, bf16 MFMA),
//                                   M += U * A_b^T (64x64x128, bf16 MFMA),
// epilogue: <S, M> per-thread from S registers, reduce, one atomicAdd.
// D symmetric => both MFMA B-operands are natural row-major: NO transposes.
// All LDS tiles XOR-swizzled: physical_byte = logical_byte ^ ((row&7)<<4).
// ---------------------------------------------------------------------------
__global__ __launch_bounds__(256, 2)
void edge_loss_v3(const float* __restrict__ P,
                  const float* __restrict__ Sf,
                  const ushort* __restrict__ Dbf,
                  float* __restrict__ out) {
    // 81920 B exactly: Db[128][128] | Ab0[64][128] | Ab1[64][128] | Ub[64][128]
    __shared__ ushort lds[40960];
    ushort* Db  = lds;
    ushort* Ab0 = lds + 16384;
    ushort* Ab1 = lds + 16384 + 8192;
    ushort* Ub  = lds + 16384 + 16384;

    const int tid  = threadIdx.x;
    const int lane = tid & 63;
    const int w    = tid >> 6;           // wave 0..3 owns M-rows [16w,16w+16)
    const int l15  = lane & 15;
    const int lg   = lane >> 4;
    const uint rmask = (uint)(l15 & 7) << 4;   // frag-read swizzle (row&7 == l15&7)
    const int rowa = 16 * w + l15;             // A-op row for U-step and M-step

    // ---- stage D bf16 -> LDS, swizzled (granule ^= row&7) ----
    {
        const uint4* src = reinterpret_cast<const uint4*>(Dbf);   // 2048 granules
        for (int k = tid; k < 2048; k += 256) {
            int row = k >> 4, gc = k & 15;
            int gs = gc ^ (row & 7);
            *reinterpret_cast<uint4*>((char*)Db + row * 256 + gs * 16) = src[k];
        }
    }

    // ---- S into registers at this thread's M-frag coordinates ----
    float sreg[4][4];
#pragma unroll
    for (int nt = 0; nt < 4; ++nt)
#pragma unroll
        for (int r = 0; r < 4; ++r)
            sreg[nt][r] = Sf[(16 * w + 4 * lg + r) * NL + nt * 16 + l15];

    f32x4 m[4];
#pragma unroll
    for (int nt = 0; nt < 4; ++nt) m[nt] = (f32x4)0.0f;

    float4 pf[8];
    const int b0 = blockIdx.x * BPB;
    auto loadA = [&](int b) {
        const float4* src = reinterpret_cast<const float4*>(P + (size_t)b * H * H);
#pragma unroll
        for (int k = 0; k < 8; ++k) pf[k] = src[tid + k * 256];
    };
    auto cvtStore = [&](ushort* dst) {
#pragma unroll
        for (int k = 0; k < 8; ++k) {
            int f4 = tid + k * 256;
            int i  = f4 >> 5;             // A row 0..63
            int q4 = (f4 & 31) * 4;       // col start
            uint2 d2;
            d2.x = pk2bf(pf[k].x, pf[k].y);
            d2.y = pk2bf(pf[k].z, pf[k].w);
            *reinterpret_cast<uint2*>((char*)dst + i * 256 + ((q4 * 2) ^ ((i & 7) << 4))) = d2;
        }
    };

    loadA(b0);
    cvtStore(Ab0);
    __syncthreads();

    for (int bb = 0; bb < BPB; ++bb) {
        const ushort* A_ = (bb & 1) ? Ab1 : Ab0;
        if (bb + 1 < BPB) loadA(b0 + bb + 1);    // issue next batch's loads early

        // ---- U = A * D : wave computes U rows [16w,16w+16), all 128 cols ----
        f32x4 u[8];
#pragma unroll
        for (int nt = 0; nt < 8; ++nt) u[nt] = (f32x4)0.0f;
#pragma unroll
        for (int ks = 0; ks < 4; ++ks) {
            const uint koff = (uint)(ks * 64 + lg * 16);
            bf16x8 a = *reinterpret_cast<const bf16x8*>((const char*)A_ + rowa * 256 + (koff ^ rmask));
#pragma unroll
            for (int nt = 0; nt < 8; ++nt) {
                bf16x8 d = *reinterpret_cast<const bf16x8*>((const char*)Db + (nt * 16 + l15) * 256 + (koff ^ rmask));
                u[nt] = __builtin_amdgcn_mfma_f32_16x16x32_bf16(a, d, u[nt], 0, 0, 0);
            }
        }
        // ---- U frags -> Ub (bf16, scalar b16 writes, swizzled; wave-private rows) ----
#pragma unroll
        for (int nt = 0; nt < 8; ++nt)
#pragma unroll
            for (int r = 0; r < 4; ++r) {
                int row = 16 * w + 4 * lg + r;
                *reinterpret_cast<ushort*>((char*)Ub + row * 256 +
                    (((uint)((nt * 16 + l15) * 2)) ^ ((uint)(row & 7) << 4))) = f2bf(u[nt][r]);
            }
        // ---- M += U * A^T : A-op = Ub own rows; B-op = A rows (natural) ----
#pragma unroll
        for (int ks = 0; ks < 4; ++ks) {
            const uint koff = (uint)(ks * 64 + lg * 16);
            bf16x8 a2 = *reinterpret_cast<const bf16x8*>((const char*)Ub + rowa * 256 + (koff ^ rmask));
#pragma unroll
            for (int nt = 0; nt < 4; ++nt) {
                bf16x8 bf = *reinterpret_cast<const bf16x8*>((const char*)A_ + (nt * 16 + l15) * 256 + (koff ^ rmask));
                m[nt] = __builtin_amdgcn_mfma_f32_16x16x32_bf16(a2, bf, m[nt], 0, 0, 0);
            }
        }
        if (bb + 1 < BPB) {
            cvtStore((bb & 1) ? Ab0 : Ab1);   // other buffer: no readers yet
            __syncthreads();                  // make it visible before next iter
        }
    }

    // ---- epilogue: <S, M> ----
    float s = 0.0f;
#pragma unroll
    for (int nt = 0; nt < 4; ++nt)
#pragma unroll
        for (int r = 0; r < 4; ++r) s = fmaf(m[nt][r], sreg[nt][r], s);
#pragma unroll
    for (int off = 32; off > 0; off >>= 1) s += __shfl_down(s, off, 64);

    __syncthreads();                 // all waves done reading Db -> safe to alias
    float* wsum = reinterpret_cast<float*>(Db);
    if (lane == 0) wsum[w] = s;
    __syncthreads();
    if (tid == 0)
        atomicAdd(out, (wsum[0] + wsum[1] + wsum[2] + wsum[3]) *
                       (1.0f / ((float)B_TOTAL * (float)NPAIRS)));
}

extern "C" void kernel_launch(void* const* d_in, const int* in_sizes, int n_in,
                              void* d_out, int out_size, void* d_ws, size_t ws_size,
                              hipStream_t stream) {
    const float* P     = (const float*)d_in[0];
    const float* Dsrc  = (const float*)d_in[1];
    const int*   pairs = (const int*)d_in[2];
    float* out = (float*)d_out;

    float*  Sf  = (float*)d_ws;                       // 16 KB
    ushort* Dbf = (ushort*)((char*)d_ws + NL * NL * 4); // 32 KB

    hipMemsetAsync(d_out, 0, sizeof(float), stream);
    prep_kernel<<<65, 256, 0, stream>>>(pairs, Dsrc, Sf, Dbf);
    edge_loss_v3<<<NBLOCKS, 256, 0, stream>>>(P, Sf, Dbf, out);
}

// Round 4
// 184.510 us; speedup vs baseline: 1.5428x; 1.0440x over previous
//
#include <hip/hip_runtime.h>
#include <hip/hip_bf16.h>

#define B_TOTAL 2048
#define H 128
#define NL 64
#define NPAIRS 512

typedef __attribute__((ext_vector_type(8))) short bf16x8;  // MFMA A/B frag (8 bf16)
typedef __attribute__((ext_vector_type(4))) float f32x4;   // MFMA C/D frag

static __device__ __forceinline__ ushort f2bf(float f) {
    uint u = __float_as_uint(f);
    u += 0x7fffu + ((u >> 16) & 1u);   // RNE
    return (ushort)(u >> 16);
}
static __device__ __forceinline__ uint pk2bf(float x, float y) {
    return (uint)f2bf(x) | ((uint)f2bf(y) << 16);
}

// ---------------------------------------------------------------------------
// prep: block 0 builds S (edge-count matrix, f32); blocks 1..64 convert
// D (symmetric 128x128 f32) to bf16 row-major.
// ws layout: float Sf[64*64] | ushort Dbf[128*128] | float partials[2048]
// ---------------------------------------------------------------------------
__global__ void prep_kernel(const int* __restrict__ pairs,
                            const float* __restrict__ Dsrc,
                            float* __restrict__ Sf,
                            ushort* __restrict__ Dbf) {
    const int tid = threadIdx.x;
    if (blockIdx.x == 0) {
        __shared__ int cnt[NL * NL];
        for (int k = tid; k < NL * NL; k += 256) cnt[k] = 0;
        __syncthreads();
        for (int e = tid; e < NPAIRS; e += 256) {
            int i = pairs[2 * e] & (NL - 1);
            int j = pairs[2 * e + 1] & (NL - 1);
            atomicAdd(&cnt[i * NL + j], 1);
        }
        __syncthreads();
        for (int k = tid; k < NL * NL; k += 256) Sf[k] = (float)cnt[k];
    } else {
        int k = (blockIdx.x - 1) * 256 + tid;   // 64 * 256 = 16384 = H*H
        Dbf[k] = f2bf(Dsrc[k]);
    }
}

// ---------------------------------------------------------------------------
// edge: one batch per block.  U = A*D (D-frags in REGISTERS, wave w owns
// U col-tiles {2w,2w+1} over all 64 rows), Ub round-trip in LDS (swizzled),
// M = U*A^T (wave w owns M row-tile w), partial <S,M> -> partials[block].
// LDS swizzle: physical_byte = row*256 + (logical_col_byte ^ ((row&15)<<4)).
// ---------------------------------------------------------------------------
__global__ __launch_bounds__(256, 3)
void edge_loss_v4(const float* __restrict__ P,
                  const float* __restrict__ Sf,
                  const ushort* __restrict__ Dbf,
                  float* __restrict__ partials) {
    __shared__ __align__(16) ushort Ab[NL * H];   // 16 KB, swizzled bf16 A
    __shared__ __align__(16) ushort Ub[NL * H];   // 16 KB, swizzled bf16 U
    __shared__ float wsum[4];

    const int tid  = threadIdx.x;
    const int lane = tid & 63;
    const int w    = tid >> 6;             // wave 0..3
    const int l15  = lane & 15;
    const int lg   = lane >> 4;            // 0..3
    const uint rmask = (uint)l15 << 4;     // frag rows are (tile*16+l15): row&15==l15
    const int b    = blockIdx.x;

    // ---- issue A loads (HBM) first ----
    float4 pf[8];
    {
        const float4* src = reinterpret_cast<const float4*>(P + (size_t)b * H * H);
#pragma unroll
        for (int k = 0; k < 8; ++k) pf[k] = src[tid + k * 256];
    }

    // ---- D frags -> registers: wave w needs D rows [32w, 32w+32) only ----
    bf16x8 dreg[2][4];
#pragma unroll
    for (int c2 = 0; c2 < 2; ++c2) {
        const int drow = (2 * w + c2) * 16 + l15;
#pragma unroll
        for (int ks = 0; ks < 4; ++ks)
            dreg[c2][ks] = *reinterpret_cast<const bf16x8*>(Dbf + drow * H + ks * 32 + lg * 8);
    }

    // ---- S values at this thread's M-frag coordinates ----
    float sreg[4][4];
#pragma unroll
    for (int nt = 0; nt < 4; ++nt)
#pragma unroll
        for (int r = 0; r < 4; ++r)
            sreg[nt][r] = Sf[(16 * w + 4 * lg + r) * NL + nt * 16 + l15];

    // ---- convert+store A -> LDS (swizzled) ----
#pragma unroll
    for (int k = 0; k < 8; ++k) {
        const int f4 = tid + k * 256;
        const int i  = f4 >> 5;                 // A row 0..63
        const uint cb = (uint)(f4 & 31) * 8;    // col byte offset 0..248
        uint2 d2;
        d2.x = pk2bf(pf[k].x, pf[k].y);
        d2.y = pk2bf(pf[k].z, pf[k].w);
        *reinterpret_cast<uint2*>((char*)Ab + i * 256 + (cb ^ ((uint)(i & 15) << 4))) = d2;
    }
    __syncthreads();

    // ---- U-step: u[it][c2] = tile (rows it*16.., cols (2w+c2)*16..) ----
    f32x4 u[4][2];
#pragma unroll
    for (int it = 0; it < 4; ++it) { u[it][0] = (f32x4)0.0f; u[it][1] = (f32x4)0.0f; }
#pragma unroll
    for (int ks = 0; ks < 4; ++ks) {
        const uint koff = (uint)(ks * 64 + lg * 16);
#pragma unroll
        for (int it = 0; it < 4; ++it) {
            bf16x8 a = *reinterpret_cast<const bf16x8*>((const char*)Ab + (it * 16 + l15) * 256 + (koff ^ rmask));
            u[it][0] = __builtin_amdgcn_mfma_f32_16x16x32_bf16(a, dreg[0][ks], u[it][0], 0, 0, 0);
            u[it][1] = __builtin_amdgcn_mfma_f32_16x16x32_bf16(a, dreg[1][ks], u[it][1], 0, 0, 0);
        }
    }
    // ---- U frags -> Ub (scalar b16, swizzled; conflict-free by construction) ----
#pragma unroll
    for (int it = 0; it < 4; ++it)
#pragma unroll
        for (int c2 = 0; c2 < 2; ++c2)
#pragma unroll
            for (int r = 0; r < 4; ++r) {
                const int row = it * 16 + 4 * lg + r;
                const uint cb = (uint)((2 * w + c2) * 16 + l15) * 2;
                *reinterpret_cast<ushort*>((char*)Ub + row * 256 + (cb ^ ((uint)(row & 15) << 4))) = f2bf(u[it][c2][r]);
            }
    __syncthreads();

    // ---- M-step: wave w computes M rows [16w,16w+16), all 64 cols ----
    f32x4 m[4];
#pragma unroll
    for (int nt = 0; nt < 4; ++nt) m[nt] = (f32x4)0.0f;
#pragma unroll
    for (int ks = 0; ks < 4; ++ks) {
        const uint koff = (uint)(ks * 64 + lg * 16);
        bf16x8 a2 = *reinterpret_cast<const bf16x8*>((const char*)Ub + (16 * w + l15) * 256 + (koff ^ rmask));
#pragma unroll
        for (int nt = 0; nt < 4; ++nt) {
            bf16x8 bfr = *reinterpret_cast<const bf16x8*>((const char*)Ab + (nt * 16 + l15) * 256 + (koff ^ rmask));
            m[nt] = __builtin_amdgcn_mfma_f32_16x16x32_bf16(a2, bfr, m[nt], 0, 0, 0);
        }
    }

    // ---- epilogue: <S, M> partial, block-reduce, one plain store ----
    float s = 0.0f;
#pragma unroll
    for (int nt = 0; nt < 4; ++nt)
#pragma unroll
        for (int r = 0; r < 4; ++r) s = fmaf(m[nt][r], sreg[nt][r], s);
#pragma unroll
    for (int off = 32; off > 0; off >>= 1) s += __shfl_down(s, off, 64);

    if (lane == 0) wsum[w] = s;
    __syncthreads();
    if (tid == 0) partials[b] = wsum[0] + wsum[1] + wsum[2] + wsum[3];
}

// ---------------------------------------------------------------------------
// finish: reduce 2048 partials, scale, write out[0] (no atomics, no memset)
// ---------------------------------------------------------------------------
__global__ void finish_kernel(const float* __restrict__ partials,
                              float* __restrict__ out) {
    __shared__ float wsum[4];
    const int tid = threadIdx.x, lane = tid & 63, w = tid >> 6;
    const float4* p4 = reinterpret_cast<const float4*>(partials);
    float s = 0.0f;
#pragma unroll
    for (int k = 0; k < 2; ++k) {
        float4 v = p4[tid + k * 256];
        s += v.x + v.y + v.z + v.w;
    }
#pragma unroll
    for (int off = 32; off > 0; off >>= 1) s += __shfl_down(s, off, 64);
    if (lane == 0) wsum[w] = s;
    __syncthreads();
    if (tid == 0)
        out[0] = (wsum[0] + wsum[1] + wsum[2] + wsum[3]) *
                 (1.0f / ((float)B_TOTAL * (float)NPAIRS));
}

extern "C" void kernel_launch(void* const* d_in, const int* in_sizes, int n_in,
                              void* d_out, int out_size, void* d_ws, size_t ws_size,
                              hipStream_t stream) {
    const float* P     = (const float*)d_in[0];
    const float* Dsrc  = (const float*)d_in[1];
    const int*   pairs = (const int*)d_in[2];
    float* out = (float*)d_out;

    float*  Sf       = (float*)d_ws;                            // 16 KB
    ushort* Dbf      = (ushort*)((char*)d_ws + NL * NL * 4);    // 32 KB
    float*  partials = (float*)((char*)d_ws + NL * NL * 4 + H * H * 2); // 8 KB

    prep_kernel<<<65, 256, 0, stream>>>(pairs, Dsrc, Sf, Dbf);
    edge_loss_v4<<<B_TOTAL, 256, 0, stream>>>(P, Sf, Dbf, partials);
    finish_kernel<<<1, 256, 0, stream>>>(partials, out);
}